// Round 9
// baseline (198.198 us; speedup 1.0000x reference)
//
#include <hip/hip_runtime.h>
#include <hip/hip_cooperative_groups.h>

namespace cg = cooperative_groups;

// Problem constants (match the JAX reference)
constexpr int Bv  = 4;
constexpr int NXv = 432;
constexpr int NYv = 496;
constexpr int Cv  = 64;
constexpr int PLANE = NYv * NXv;          // 214272 cells per (b) grid
constexpr int GRID_CELLS = Bv * PLANE;    // 857088 cells per tensor
constexpr int PER_TENSOR_T4 = GRID_CELLS / 4;  // 214272 gather items per tensor
constexpr int GATHER_ITEMS  = 2 * PER_TENSOR_T4;      // 428544
constexpr int FULL_BLOCKS   = GATHER_ITEMS / 256;     // 1674: one item per thread
// map (2*GRID_CELLS ints) + zero_row (64 floats), in int4 units
constexpr int ZTOT4 = (2 * GRID_CELLS + Cv) / 4;

typedef float v4f __attribute__((ext_vector_type(4)));

// ---------------------------------------------------------------------------
// R4-exact gather body, shared by both paths.
// ---------------------------------------------------------------------------
__device__ __forceinline__ void gather_item(
        int it, const int* __restrict__ map,
        const float* __restrict__ t_feats, const float* __restrict__ s_feats,
        const float* __restrict__ zero_row, float* __restrict__ out, size_t half) {
    const int which = (it >= PER_TENSOR_T4) ? 1 : 0;   // wave-uniform
    const int lid = it - which * PER_TENSOR_T4;

    const int*   mp    = map + which * GRID_CELLS;
    const float* feats = which ? s_feats : t_feats;
    float*       obase = out + (which ? half : 0);

    const int g = lid * 4;                 // b*PLANE + y*NX + x
    const int b = lid / (PLANE / 4);       // wave-uniform

    const int4 m = *reinterpret_cast<const int4*>(mp + g);

    const float* p0 = (m.x > 0) ? feats + (size_t)(m.x - 1) * Cv : zero_row;
    const float* p1 = (m.y > 0) ? feats + (size_t)(m.y - 1) * Cv : zero_row;
    const float* p2 = (m.z > 0) ? feats + (size_t)(m.z - 1) * Cv : zero_row;
    const float* p3 = (m.w > 0) ? feats + (size_t)(m.w - 1) * Cv : zero_row;

    float* o = obase + g + (size_t)b * (Cv - 1) * PLANE;

    for (int ch = 0; ch < 4; ++ch) {       // 16 channels per chunk
        const int cb = ch * 16;
        v4f r0[4], r1[4], r2[4], r3[4];
        #pragma unroll
        for (int j = 0; j < 4; ++j) {
            r0[j] = *reinterpret_cast<const v4f*>(p0 + cb + j * 4);
            r1[j] = *reinterpret_cast<const v4f*>(p1 + cb + j * 4);
            r2[j] = *reinterpret_cast<const v4f*>(p2 + cb + j * 4);
            r3[j] = *reinterpret_cast<const v4f*>(p3 + cb + j * 4);
        }
        #pragma unroll
        for (int j = 0; j < 4; ++j) {
            const v4f s0 = {r0[j].x, r1[j].x, r2[j].x, r3[j].x};
            const v4f s1 = {r0[j].y, r1[j].y, r2[j].y, r3[j].y};
            const v4f s2 = {r0[j].z, r1[j].z, r2[j].z, r3[j].z};
            const v4f s3 = {r0[j].w, r1[j].w, r2[j].w, r3[j].w};
            __builtin_nontemporal_store(s0, reinterpret_cast<v4f*>(o + (size_t)(cb + j * 4 + 0) * PLANE));
            __builtin_nontemporal_store(s1, reinterpret_cast<v4f*>(o + (size_t)(cb + j * 4 + 1) * PLANE));
            __builtin_nontemporal_store(s2, reinterpret_cast<v4f*>(o + (size_t)(cb + j * 4 + 2) * PLANE));
            __builtin_nontemporal_store(s3, reinterpret_cast<v4f*>(o + (size_t)(cb + j * 4 + 3) * PLANE));
        }
    }
}

// ---------------------------------------------------------------------------
// Single cooperative kernel: zero map -> sync -> scatter coords -> sync ->
// gather. All phases grid-stride: correct for ANY grid size.
// ---------------------------------------------------------------------------
__global__ __launch_bounds__(256) void fused_all_kernel(
        const int* __restrict__ t_coords, int nt,
        const int* __restrict__ s_coords, int ns,
        const float* __restrict__ t_feats,
        const float* __restrict__ s_feats,
        int* __restrict__ map,          // [2*GRID_CELLS] ints + 64-float zero row
        float* __restrict__ out, size_t half) {
    cg::grid_group grid = cg::this_grid();
    const int nth = gridDim.x * blockDim.x;
    const int tid = blockIdx.x * blockDim.x + threadIdx.x;

    // ---- Phase A: zero map + zero_row ----
    {
        const int4 z = {0, 0, 0, 0};
        int4* m4 = reinterpret_cast<int4*>(map);
        for (int i = tid; i < ZTOT4; i += nth) m4[i] = z;
    }
    grid.sync();

    // ---- Phase B: scatter voxel index (i+1); unique indices -> race-free ----
    for (int i = tid; i < nt + ns; i += nth) {
        if (i < nt) {
            const int4 c = reinterpret_cast<const int4*>(t_coords)[i]; // b,z,y,x
            map[(c.x * NYv + c.z) * NXv + c.w] = i + 1;
        } else {
            const int j = i - nt;
            const int4 c = reinterpret_cast<const int4*>(s_coords)[j];
            map[GRID_CELLS + (c.x * NYv + c.z) * NXv + c.w] = j + 1;
        }
    }
    grid.sync();

    // ---- Phase C: gather ----
    const float* zero_row = reinterpret_cast<const float*>(map + 2 * GRID_CELLS);
    for (int it = tid; it < GATHER_ITEMS; it += nth)
        gather_item(it, map, t_feats, s_feats, zero_row, out, half);
}

// ---------------------------------------------------------------------------
// Proven R4 fallback path: memset + build + gather (93.7 us).
// ---------------------------------------------------------------------------
__global__ void build_all_kernel(const int* __restrict__ t_coords, int nt,
                                 const int* __restrict__ s_coords, int ns,
                                 int* __restrict__ map) {
    int i = blockIdx.x * blockDim.x + threadIdx.x;
    if (i < nt) {
        const int4 c = reinterpret_cast<const int4*>(t_coords)[i];
        map[(c.x * NYv + c.z) * NXv + c.w] = i + 1;
    } else if (i < nt + ns) {
        int j = i - nt;
        const int4 c = reinterpret_cast<const int4*>(s_coords)[j];
        map[GRID_CELLS + (c.x * NYv + c.z) * NXv + c.w] = j + 1;
    }
}

__global__ __launch_bounds__(256) void gather_all_kernel(
        const int* __restrict__ map,
        const float* __restrict__ t_feats,
        const float* __restrict__ s_feats,
        const float* __restrict__ zero_row,
        float* __restrict__ out, size_t half) {
    int tid = blockIdx.x * blockDim.x + threadIdx.x;
    gather_item(tid, map, t_feats, s_feats, zero_row, out, half);
}

extern "C" void kernel_launch(void* const* d_in, const int* in_sizes, int n_in,
                              void* d_out, int out_size, void* d_ws, size_t ws_size,
                              hipStream_t stream) {
    const float* t_feats  = (const float*)d_in[0];
    const int*   t_coords = (const int*)d_in[1];
    const float* s_feats  = (const float*)d_in[2];
    const int*   s_coords = (const int*)d_in[3];
    float* out = (float*)d_out;

    int NT = in_sizes[0] / Cv;  // 16384 template voxels
    int NS = in_sizes[2] / Cv;  // 65536 search voxels
    size_t half = (size_t)out_size / 2;

    const size_t map_bytes = 2ull * GRID_CELLS * sizeof(int);
    const size_t ws_need   = map_bytes + 256;  // maps + zero row

    if (ws_size < ws_need) return;  // harness guarantees ample ws; nothing sane to do

    int* map = (int*)d_ws;
    const float* zero_row = (const float*)((char*)d_ws + map_bytes);

    // --- Try cooperative single-dispatch path (grid sized by occupancy query) ---
    int perCU = 0;
    hipError_t qe = hipOccupancyMaxActiveBlocksPerMultiprocessor(
        &perCU, reinterpret_cast<const void*>(fused_all_kernel), 256, 0);

    bool coop_done = false;
    if (qe == hipSuccess && perCU > 0) {
        int blocks = perCU * 256;            // 256 CUs on MI355X
        if (blocks > FULL_BLOCKS) blocks = FULL_BLOCKS;
        void* args[] = {&t_coords, &NT, &s_coords, &NS,
                        &t_feats, &s_feats, &map, &out, &half};
        hipError_t le = hipLaunchCooperativeKernel(
            (const void*)fused_all_kernel, dim3(blocks), dim3(256), args, 0, stream);
        coop_done = (le == hipSuccess);
    }

    if (!coop_done) {
        // --- Proven 3-dispatch path (R4, 93.7 us) ---
        (void)hipMemsetAsync(d_ws, 0, ws_need, stream);
        build_all_kernel<<<(NT + NS + 255) / 256, 256, 0, stream>>>(
            t_coords, NT, s_coords, NS, map);
        gather_all_kernel<<<FULL_BLOCKS, 256, 0, stream>>>(
            map, t_feats, s_feats, zero_row, out, half);
    }
}

// Round 10
// 94.450 us; speedup vs baseline: 2.0984x; 2.0984x over previous
//
#include <hip/hip_runtime.h>

// Problem constants (match the JAX reference)
constexpr int Bv  = 4;
constexpr int NXv = 432;
constexpr int NYv = 496;
constexpr int Cv  = 64;
constexpr int PLANE = NYv * NXv;          // 214272 cells per (b) grid
constexpr int GRID_CELLS = Bv * PLANE;    // 857088 cells per tensor
constexpr int PER_TENSOR_T4 = GRID_CELLS / 4;  // 214272 threads per tensor (4 cells each)

typedef float v4f __attribute__((ext_vector_type(4)));

// ---------------------------------------------------------------------------
// Kernel 1: fused scatter of voxel row index (i+1) into map for both tensors.
// map default is 0 (single memset covers map + zero_row). Indices unique.
// coords row layout: (b, z, y, x), z == 0.
// ---------------------------------------------------------------------------
__global__ void build_all_kernel(const int* __restrict__ t_coords, int nt,
                                 const int* __restrict__ s_coords, int ns,
                                 int* __restrict__ map) {
    int i = blockIdx.x * blockDim.x + threadIdx.x;
    if (i < nt) {
        const int4 c = reinterpret_cast<const int4*>(t_coords)[i]; // b,z,y,x
        map[(c.x * NYv + c.z) * NXv + c.w] = i + 1;
    } else if (i < nt + ns) {
        int j = i - nt;
        const int4 c = reinterpret_cast<const int4*>(s_coords)[j];
        map[GRID_CELLS + (c.x * NYv + c.z) * NXv + c.w] = j + 1;
    }
}

// ---------------------------------------------------------------------------
// Kernel 2: fused gather for BOTH output tensors (R4-exact, best measured).
// One thread per 4 consecutive x-cells. Per thread: pick 4 source-row
// pointers once, then 4 chunks of 16 channels. Per chunk: batch-load
// 16 float4 (4 consecutive per row = full 64B line consumed at once),
// then batch-store 16 transposed float4 with nontemporal hint.
// Tensor/batch splits land on exact wave boundaries.
// ---------------------------------------------------------------------------
__global__ __launch_bounds__(256) void gather_all_kernel(
        const int* __restrict__ map,
        const float* __restrict__ t_feats,
        const float* __restrict__ s_feats,
        const float* __restrict__ zero_row,
        float* __restrict__ out, size_t half) {
    int tid = blockIdx.x * blockDim.x + threadIdx.x;
    const int which = (tid >= PER_TENSOR_T4) ? 1 : 0;  // wave-uniform (214272 % 64 == 0)
    const int lid = tid - which * PER_TENSOR_T4;

    const int*   mp    = map + which * GRID_CELLS;
    const float* feats = which ? s_feats : t_feats;
    float*       obase = out + (which ? half : 0);

    const int g = lid * 4;                 // first cell index (b*PLANE + y*NX + x)
    const int b = lid / (PLANE / 4);       // wave-uniform (53568 % 64 == 0)

    const int4 m = *reinterpret_cast<const int4*>(mp + g);

    const float* p0 = (m.x > 0) ? feats + (size_t)(m.x - 1) * Cv : zero_row;
    const float* p1 = (m.y > 0) ? feats + (size_t)(m.y - 1) * Cv : zero_row;
    const float* p2 = (m.z > 0) ? feats + (size_t)(m.z - 1) * Cv : zero_row;
    const float* p3 = (m.w > 0) ? feats + (size_t)(m.w - 1) * Cv : zero_row;

    // out[b][c][y][x]: offset = g + b*(Cv-1)*PLANE + c*PLANE
    float* o = obase + g + (size_t)b * (Cv - 1) * PLANE;

    for (int ch = 0; ch < 4; ++ch) {       // 16 channels per chunk
        const int cb = ch * 16;
        v4f r0[4], r1[4], r2[4], r3[4];
        // ---- load phase: 16 loads, 64B contiguous per row ----
        #pragma unroll
        for (int j = 0; j < 4; ++j) {
            r0[j] = *reinterpret_cast<const v4f*>(p0 + cb + j * 4);
            r1[j] = *reinterpret_cast<const v4f*>(p1 + cb + j * 4);
            r2[j] = *reinterpret_cast<const v4f*>(p2 + cb + j * 4);
            r3[j] = *reinterpret_cast<const v4f*>(p3 + cb + j * 4);
        }
        // ---- store phase: 16 transposed nontemporal stores ----
        #pragma unroll
        for (int j = 0; j < 4; ++j) {
            const v4f s0 = {r0[j].x, r1[j].x, r2[j].x, r3[j].x};
            const v4f s1 = {r0[j].y, r1[j].y, r2[j].y, r3[j].y};
            const v4f s2 = {r0[j].z, r1[j].z, r2[j].z, r3[j].z};
            const v4f s3 = {r0[j].w, r1[j].w, r2[j].w, r3[j].w};
            __builtin_nontemporal_store(s0, reinterpret_cast<v4f*>(o + (size_t)(cb + j * 4 + 0) * PLANE));
            __builtin_nontemporal_store(s1, reinterpret_cast<v4f*>(o + (size_t)(cb + j * 4 + 1) * PLANE));
            __builtin_nontemporal_store(s2, reinterpret_cast<v4f*>(o + (size_t)(cb + j * 4 + 2) * PLANE));
            __builtin_nontemporal_store(s3, reinterpret_cast<v4f*>(o + (size_t)(cb + j * 4 + 3) * PLANE));
        }
    }
}

// ---------------------------------------------------------------------------
// Fallback (only if ws too small): direct scatter after zeroing output.
// ---------------------------------------------------------------------------
__global__ void direct_scatter_kernel(const float* __restrict__ feats,
                                      const int* __restrict__ coords, int n,
                                      float* __restrict__ out) {
    int i = blockIdx.x * blockDim.x + threadIdx.x;
    if (i >= n * Cv) return;
    int v = i >> 6;
    int c = i & 63;
    int b = coords[v * 4 + 0];
    int y = coords[v * 4 + 2];
    int x = coords[v * 4 + 3];
    out[((size_t)(b * Cv + c) * NYv + y) * NXv + x] = feats[(size_t)v * Cv + c];
}

extern "C" void kernel_launch(void* const* d_in, const int* in_sizes, int n_in,
                              void* d_out, int out_size, void* d_ws, size_t ws_size,
                              hipStream_t stream) {
    const float* t_feats  = (const float*)d_in[0];
    const int*   t_coords = (const int*)d_in[1];
    const float* s_feats  = (const float*)d_in[2];
    const int*   s_coords = (const int*)d_in[3];
    float* out = (float*)d_out;

    const int NT = in_sizes[0] / Cv;  // 16384 template voxels
    const int NS = in_sizes[2] / Cv;  // 65536 search voxels
    const size_t half = (size_t)out_size / 2;

    const size_t map_bytes = 2ull * GRID_CELLS * sizeof(int);
    const size_t ws_need   = map_bytes + 256;  // maps + zero row

    if (ws_size >= ws_need) {
        int* map = (int*)d_ws;
        const float* zero_row = (const float*)((char*)d_ws + map_bytes);

        // One memset: maps -> 0 (invalid), zero_row -> 0.0f
        (void)hipMemsetAsync(d_ws, 0, ws_need, stream);

        build_all_kernel<<<(NT + NS + 255) / 256, 256, 0, stream>>>(
            t_coords, NT, s_coords, NS, map);

        const int gthreads = 2 * PER_TENSOR_T4;            // 428544
        gather_all_kernel<<<gthreads / 256, 256, 0, stream>>>(
            map, t_feats, s_feats, zero_row, out, half);
    } else {
        (void)hipMemsetAsync(d_out, 0, (size_t)out_size * sizeof(float), stream);
        direct_scatter_kernel<<<(NT * Cv + 255) / 256, 256, 0, stream>>>(
            t_feats, t_coords, NT, out);
        direct_scatter_kernel<<<(NS * Cv + 255) / 256, 256, 0, stream>>>(
            s_feats, s_coords, NS, out + half);
    }
}